// Round 1
// baseline (1175.113 us; speedup 1.0000x reference)
//
#include <hip/hip_runtime.h>
#include <hip/hip_bf16.h>

#define D 256
#define G 512
#define PER 128
#define NROW (G*PER)   // 65536
#define LSEQ 1534
#define LP 1536
#define HID 512

typedef __hip_bfloat16 bf16;

// ---------------------------------------------------------------------------
// K1: hats = relu(NEs @ Wa + ba)  (stored bf16), HAts = per-group max (f32)
// one block per group (128 rows), 256 threads, 4 passes of 32 rows
// thread (tx,ty): 8 rows x 4 cols register tile
// ---------------------------------------------------------------------------
__global__ __launch_bounds__(256) void k_hats(
    const float* __restrict__ NEs, const float* __restrict__ Wa,
    const float* __restrict__ ba, bf16* __restrict__ hats,
    float* __restrict__ HAts) {
  __shared__ __align__(16) float lds_a[32][D];   // 32 KB
  __shared__ float smax[4][D];                   // 4 KB
  const int tid = threadIdx.x;
  const int tx = tid & 63, ty = tid >> 6;
  const int g = blockIdx.x;
  float bav[4], colmax[4];
  #pragma unroll
  for (int j = 0; j < 4; ++j) { bav[j] = ba[tx + 64*j]; colmax[j] = 0.f; }

  for (int pass = 0; pass < 4; ++pass) {
    __syncthreads();
    const float4* src = (const float4*)(NEs + (size_t)(g*PER + pass*32) * D);
    float4* dst = (float4*)(&lds_a[0][0]);
    #pragma unroll
    for (int i = 0; i < 8; ++i) dst[i*256 + tid] = src[i*256 + tid];
    __syncthreads();

    float acc[8][4];
    #pragma unroll
    for (int i = 0; i < 8; ++i)
      #pragma unroll
      for (int j = 0; j < 4; ++j) acc[i][j] = 0.f;

    for (int k4 = 0; k4 < D/4; ++k4) {
      float4 av[8];
      #pragma unroll
      for (int i = 0; i < 8; ++i) av[i] = *(const float4*)&lds_a[ty*8 + i][k4*4];
      #pragma unroll
      for (int kk = 0; kk < 4; ++kk) {
        const float* wrow = Wa + (size_t)(k4*4 + kk) * D;
        float w[4];
        #pragma unroll
        for (int j = 0; j < 4; ++j) w[j] = wrow[tx + 64*j];
        #pragma unroll
        for (int i = 0; i < 8; ++i) {
          float a = ((const float*)&av[i])[kk];
          #pragma unroll
          for (int j = 0; j < 4; ++j) acc[i][j] = fmaf(a, w[j], acc[i][j]);
        }
      }
    }
    #pragma unroll
    for (int i = 0; i < 8; ++i) {
      size_t row = (size_t)(g*PER + pass*32 + ty*8 + i);
      #pragma unroll
      for (int j = 0; j < 4; ++j) {
        float h = acc[i][j] + bav[j];
        h = h > 0.f ? h : 0.f;
        colmax[j] = fmaxf(colmax[j], h);
        hats[row*D + tx + 64*j] = __float2bfloat16(h);   // exact max kept in f32
      }
    }
  }
  #pragma unroll
  for (int j = 0; j < 4; ++j) smax[ty][tx + 64*j] = colmax[j];
  __syncthreads();
  if (ty == 0) {
    #pragma unroll
    for (int j = 0; j < 4; ++j) {
      int c = tx + 64*j;
      HAts[g*D + c] = fmaxf(fmaxf(smax[0][c], smax[1][c]),
                            fmaxf(smax[2][c], smax[3][c]));
    }
  }
}

// ---------------------------------------------------------------------------
// K2: build x0 (C=256, L=1534) transposed sequence
// row 3g = nodes[g], 3g+1 = HAts[g], 3g+2 = hats[g*128+act[g]] (g<511), 1533 = nodes[511]
// ---------------------------------------------------------------------------
__global__ void k_build_x0(const float* __restrict__ nodes,
                           const float* __restrict__ HAts,
                           const bf16* __restrict__ hats,
                           const int* __restrict__ act,
                           float* __restrict__ x0) {
  int t = blockIdx.x * 256 + threadIdx.x;
  int c = blockIdx.y;
  if (t >= LSEQ) return;
  float v;
  if (t == LSEQ - 1) {
    v = nodes[(size_t)(G-1)*D + c];
  } else {
    int r = t / 3, m = t - 3*r;
    if (m == 0)      v = nodes[(size_t)r*D + c];
    else if (m == 1) v = HAts[(size_t)r*D + c];
    else             v = __bfloat162float(hats[(size_t)(r*PER + act[r])*D + c]);
  }
  x0[(size_t)c*LP + t] = v;
}

// ---------------------------------------------------------------------------
// K3: one TCN layer. y = relu(causal_conv(x)+b); out = relu(y + res)
// res = x (Wd==null) or Wd@x. block: 256 t-threads x 8 output channels
// ---------------------------------------------------------------------------
__global__ __launch_bounds__(256) void k_tcn(
    const float* __restrict__ xin, float* __restrict__ xout,
    const float* __restrict__ W,   // (Cout, Cin, 3)
    const float* __restrict__ b,
    const float* __restrict__ Wd,  // (Cout, Cin) or null
    int Cin, int dil) {
  int t = blockIdx.x * 256 + threadIdx.x;
  int o0 = blockIdx.y * 8;
  if (t >= LSEQ) return;
  float acc[8], res[8];
  #pragma unroll
  for (int oo = 0; oo < 8; ++oo) { acc[oo] = b[o0 + oo]; res[oo] = 0.f; }
  const bool has1 = (t >= dil), has0 = (t >= 2*dil);
  for (int i = 0; i < Cin; ++i) {
    float x2  = xin[(size_t)i*LP + t];
    float x1  = has1 ? xin[(size_t)i*LP + t - dil]   : 0.f;
    float x0v = has0 ? xin[(size_t)i*LP + t - 2*dil] : 0.f;
    #pragma unroll
    for (int oo = 0; oo < 8; ++oo) {
      const float* w = &W[((size_t)(o0+oo)*Cin + i)*3];
      acc[oo] = fmaf(w[0], x0v, acc[oo]);
      acc[oo] = fmaf(w[1], x1,  acc[oo]);
      acc[oo] = fmaf(w[2], x2,  acc[oo]);
    }
    if (Wd) {
      #pragma unroll
      for (int oo = 0; oo < 8; ++oo)
        res[oo] = fmaf(Wd[(size_t)(o0+oo)*Cin + i], x2, res[oo]);
    }
  }
  #pragma unroll
  for (int oo = 0; oo < 8; ++oo) {
    float y = acc[oo] > 0.f ? acc[oo] : 0.f;
    float r = Wd ? res[oo] : xin[(size_t)(o0+oo)*LP + t];
    float v = y + r;
    xout[(size_t)(o0+oo)*LP + t] = v > 0.f ? v : 0.f;
  }
}

// ---------------------------------------------------------------------------
// K4: Gterm[g][j] = bp1[j] + sum_{m<768} [query|hs|HAts][g][m] * Wp1[m][j]
// block: 8 groups, 256 threads -> each thread 2 cols
// ---------------------------------------------------------------------------
__global__ __launch_bounds__(256) void k_gterm(
    const float* __restrict__ query, const float* __restrict__ HAts,
    const float* __restrict__ xfin,  // final TCN output (256ch, LP)
    const float* __restrict__ Wp1, const float* __restrict__ bp1,
    float* __restrict__ Gterm) {
  __shared__ __align__(16) float s[8][768];  // 24 KB
  const int tid = threadIdx.x;
  const int g0 = blockIdx.x * 8;
  for (int gg = 0; gg < 8; ++gg) {
    int g = g0 + gg;
    s[gg][tid]       = query[(size_t)g*D + tid];
    s[gg][256 + tid] = xfin[(size_t)tid*LP + 3*g];  // hs[g][tid]
    s[gg][512 + tid] = HAts[(size_t)g*D + tid];
  }
  __syncthreads();
  float acc[8][2];
  #pragma unroll
  for (int gg = 0; gg < 8; ++gg) { acc[gg][0] = 0.f; acc[gg][1] = 0.f; }
  for (int m4 = 0; m4 < 768/4; ++m4) {
    float4 sv[8];
    #pragma unroll
    for (int gg = 0; gg < 8; ++gg) sv[gg] = *(const float4*)&s[gg][m4*4];
    #pragma unroll
    for (int kk = 0; kk < 4; ++kk) {
      int m = m4*4 + kk;
      float w0 = Wp1[(size_t)m*HID + tid];
      float w1 = Wp1[(size_t)m*HID + tid + 256];
      #pragma unroll
      for (int gg = 0; gg < 8; ++gg) {
        float a = ((const float*)&sv[gg])[kk];
        acc[gg][0] = fmaf(a, w0, acc[gg][0]);
        acc[gg][1] = fmaf(a, w1, acc[gg][1]);
      }
    }
  }
  float b0 = bp1[tid], b1 = bp1[tid + 256];
  for (int gg = 0; gg < 8; ++gg) {
    Gterm[(size_t)(g0+gg)*HID + tid]       = acc[gg][0] + b0;
    Gterm[(size_t)(g0+gg)*HID + tid + 256] = acc[gg][1] + b1;
  }
}

// ---------------------------------------------------------------------------
// K5: per row i: h = relu(Gterm[g] + hats[i] @ Wp1[768:1024]); out = h.Wp2 + bp2
// block: 32 rows x 512 cols, K=256. thread (tx,ty): 8 rows x 8 cols
// ---------------------------------------------------------------------------
__global__ __launch_bounds__(256) void k_final(
    const bf16* __restrict__ hats, const float* __restrict__ Wp1,
    const float* __restrict__ Wp2, const float* __restrict__ bp2,
    const float* __restrict__ Gterm, float* __restrict__ out) {
  __shared__ __align__(16) float lds_a[32][D];  // 32 KB
  const int tid = threadIdx.x;
  const int tx = tid & 63, ty = tid >> 6;
  const int row0 = blockIdx.x * 32;
  const int g = row0 / PER;

  // stage 32x256 hats (bf16 -> f32)
  const uint4* s4 = (const uint4*)(hats + (size_t)row0 * D);
  #pragma unroll
  for (int cth = 0; cth < 4; ++cth) {
    uint4 v = s4[cth*256 + tid];
    const unsigned short* u = (const unsigned short*)&v;
    float* dstp = &lds_a[0][0] + (size_t)(cth*256 + tid) * 8;
    float4 f0, f1;
    f0.x = __bfloat162float(*(const bf16*)&u[0]);
    f0.y = __bfloat162float(*(const bf16*)&u[1]);
    f0.z = __bfloat162float(*(const bf16*)&u[2]);
    f0.w = __bfloat162float(*(const bf16*)&u[3]);
    f1.x = __bfloat162float(*(const bf16*)&u[4]);
    f1.y = __bfloat162float(*(const bf16*)&u[5]);
    f1.z = __bfloat162float(*(const bf16*)&u[6]);
    f1.w = __bfloat162float(*(const bf16*)&u[7]);
    *(float4*)(dstp)     = f0;
    *(float4*)(dstp + 4) = f1;
  }
  __syncthreads();

  float acc[8][8];
  #pragma unroll
  for (int i = 0; i < 8; ++i)
    #pragma unroll
    for (int j = 0; j < 8; ++j) acc[i][j] = 0.f;

  for (int k4 = 0; k4 < D/4; ++k4) {
    float4 av[8];
    #pragma unroll
    for (int i = 0; i < 8; ++i) av[i] = *(const float4*)&lds_a[ty*8 + i][k4*4];
    #pragma unroll
    for (int kk = 0; kk < 4; ++kk) {
      const float* wrow = Wp1 + (size_t)(768 + k4*4 + kk) * HID;
      float w[8];
      #pragma unroll
      for (int j = 0; j < 8; ++j) w[j] = wrow[tx + 64*j];
      #pragma unroll
      for (int i = 0; i < 8; ++i) {
        float a = ((const float*)&av[i])[kk];
        #pragma unroll
        for (int j = 0; j < 8; ++j) acc[i][j] = fmaf(a, w[j], acc[i][j]);
      }
    }
  }

  float gt[8], wp[8];
  #pragma unroll
  for (int j = 0; j < 8; ++j) {
    gt[j] = Gterm[(size_t)g*HID + tx + 64*j];
    wp[j] = Wp2[tx + 64*j];
  }
  float b2 = bp2[0];
  #pragma unroll
  for (int i = 0; i < 8; ++i) {
    float local = 0.f;
    #pragma unroll
    for (int j = 0; j < 8; ++j) {
      float h = acc[i][j] + gt[j];
      h = h > 0.f ? h : 0.f;
      local = fmaf(h, wp[j], local);
    }
    #pragma unroll
    for (int off = 32; off > 0; off >>= 1) local += __shfl_xor(local, off, 64);
    if (tx == 0) out[row0 + ty*8 + i] = local + b2;
  }
}

// ---------------------------------------------------------------------------
extern "C" void kernel_launch(void* const* d_in, const int* in_sizes, int n_in,
                              void* d_out, int out_size, void* d_ws, size_t ws_size,
                              hipStream_t stream) {
  (void)in_sizes; (void)n_in; (void)out_size; (void)ws_size;
  const float* NEs   = (const float*)d_in[0];
  const float* nodes = (const float*)d_in[1];
  const float* query = (const float*)d_in[2];
  const int*   act   = (const int*)d_in[4];   // num_neighbors (d_in[3]) fixed at 128
  const float* Wa    = (const float*)d_in[5];
  const float* ba    = (const float*)d_in[6];
  const float* Wc0   = (const float*)d_in[7];
  const float* bc0   = (const float*)d_in[8];
  const float* Wc1   = (const float*)d_in[9];
  const float* bc1   = (const float*)d_in[10];
  const float* Wd1   = (const float*)d_in[11];
  const float* Wc2   = (const float*)d_in[12];
  const float* bc2   = (const float*)d_in[13];
  const float* Wc3   = (const float*)d_in[14];
  const float* bc3   = (const float*)d_in[15];
  const float* Wd3   = (const float*)d_in[16];
  const float* Wp1   = (const float*)d_in[17];
  const float* bp1   = (const float*)d_in[18];
  const float* Wp2   = (const float*)d_in[19];
  const float* bp2   = (const float*)d_in[20];
  float* out = (float*)d_out;

  char* ws = (char*)d_ws;
  bf16*  hats  = (bf16*)ws;  ws += (size_t)NROW * D * sizeof(bf16);
  float* HAts  = (float*)ws; ws += (size_t)G * D * sizeof(float);
  float* xa    = (float*)ws; ws += (size_t)512 * LP * sizeof(float);
  float* xb    = (float*)ws; ws += (size_t)512 * LP * sizeof(float);
  float* Gterm = (float*)ws; ws += (size_t)G * HID * sizeof(float);

  k_hats<<<G, 256, 0, stream>>>(NEs, Wa, ba, hats, HAts);
  k_build_x0<<<dim3(6, 256), 256, 0, stream>>>(nodes, HAts, hats, act, xa);
  k_tcn<<<dim3(6, 256/8), 256, 0, stream>>>(xa, xb, Wc0, bc0, nullptr, 256, 1);
  k_tcn<<<dim3(6, 512/8), 256, 0, stream>>>(xb, xa, Wc1, bc1, Wd1,     256, 2);
  k_tcn<<<dim3(6, 512/8), 256, 0, stream>>>(xa, xb, Wc2, bc2, nullptr, 512, 4);
  k_tcn<<<dim3(6, 256/8), 256, 0, stream>>>(xb, xa, Wc3, bc3, Wd3,     512, 8);
  k_gterm<<<G/8, 256, 0, stream>>>(query, HAts, xa, Wp1, bp1, Gterm);
  k_final<<<NROW/32, 256, 0, stream>>>(hats, Wp1, Wp2, bp2, Gterm, out);
}

// Round 2
// 994.317 us; speedup vs baseline: 1.1818x; 1.1818x over previous
//
#include <hip/hip_runtime.h>
#include <hip/hip_bf16.h>

#define D 256
#define G 512
#define PER 128
#define NROW (G*PER)   // 65536
#define LSEQ 1534
#define LP 1536
#define HID 512

typedef __hip_bfloat16 bf16;
typedef __attribute__((ext_vector_type(8))) short bf16x8;
typedef __attribute__((ext_vector_type(4))) float f32x4;

// ---------------------------------------------------------------------------
// K1: hats = relu(NEs @ Wa + ba)  (stored bf16), HAts = per-group max (f32)
// ---------------------------------------------------------------------------
__global__ __launch_bounds__(256) void k_hats(
    const float* __restrict__ NEs, const float* __restrict__ Wa,
    const float* __restrict__ ba, bf16* __restrict__ hats,
    float* __restrict__ HAts) {
  __shared__ __align__(16) float lds_a[32][D];   // 32 KB
  __shared__ float smax[4][D];                   // 4 KB
  const int tid = threadIdx.x;
  const int tx = tid & 63, ty = tid >> 6;
  const int g = blockIdx.x;
  float bav[4], colmax[4];
  #pragma unroll
  for (int j = 0; j < 4; ++j) { bav[j] = ba[tx + 64*j]; colmax[j] = 0.f; }

  for (int pass = 0; pass < 4; ++pass) {
    __syncthreads();
    const float4* src = (const float4*)(NEs + (size_t)(g*PER + pass*32) * D);
    float4* dst = (float4*)(&lds_a[0][0]);
    #pragma unroll
    for (int i = 0; i < 8; ++i) dst[i*256 + tid] = src[i*256 + tid];
    __syncthreads();

    float acc[8][4];
    #pragma unroll
    for (int i = 0; i < 8; ++i)
      #pragma unroll
      for (int j = 0; j < 4; ++j) acc[i][j] = 0.f;

    for (int k4 = 0; k4 < D/4; ++k4) {
      float4 av[8];
      #pragma unroll
      for (int i = 0; i < 8; ++i) av[i] = *(const float4*)&lds_a[ty*8 + i][k4*4];
      #pragma unroll
      for (int kk = 0; kk < 4; ++kk) {
        const float* wrow = Wa + (size_t)(k4*4 + kk) * D;
        float w[4];
        #pragma unroll
        for (int j = 0; j < 4; ++j) w[j] = wrow[tx + 64*j];
        #pragma unroll
        for (int i = 0; i < 8; ++i) {
          float a = ((const float*)&av[i])[kk];
          #pragma unroll
          for (int j = 0; j < 4; ++j) acc[i][j] = fmaf(a, w[j], acc[i][j]);
        }
      }
    }
    #pragma unroll
    for (int i = 0; i < 8; ++i) {
      size_t row = (size_t)(g*PER + pass*32 + ty*8 + i);
      #pragma unroll
      for (int j = 0; j < 4; ++j) {
        float h = acc[i][j] + bav[j];
        h = h > 0.f ? h : 0.f;
        colmax[j] = fmaxf(colmax[j], h);
        hats[row*D + tx + 64*j] = __float2bfloat16(h);
      }
    }
  }
  #pragma unroll
  for (int j = 0; j < 4; ++j) smax[ty][tx + 64*j] = colmax[j];
  __syncthreads();
  if (ty == 0) {
    #pragma unroll
    for (int j = 0; j < 4; ++j) {
      int c = tx + 64*j;
      HAts[g*D + c] = fmaxf(fmaxf(smax[0][c], smax[1][c]),
                            fmaxf(smax[2][c], smax[3][c]));
    }
  }
}

// ---------------------------------------------------------------------------
// K-wconv: Wp1 rows 768..1023 (fp32) -> MFMA-tiled bf16 layout WBt.
// flat(k,n) = (n>>7)*32768 + ((((n>>4)&7)*8 + (k>>5))*16 + (n&15))*32
//             + ((k>>3)&3)*8 + (k&7)
// ---------------------------------------------------------------------------
__global__ void k_wconv(const float* __restrict__ Wp1, bf16* __restrict__ WBt) {
  int id = blockIdx.x * 256 + threadIdx.x;   // id = k*512 + n
  int k = id >> 9, n = id & 511;
  float v = Wp1[(size_t)(768 + k) * HID + n];
  int dst = (n >> 7) * 32768
          + (((((n >> 4) & 7) * 8 + (k >> 5)) * 16 + (n & 15)) * 4 + ((k >> 3) & 3)) * 8
          + (k & 7);
  WBt[dst] = __float2bfloat16(v);
}

// ---------------------------------------------------------------------------
// K2: build x0 (C=256, L=1534) transposed sequence
// ---------------------------------------------------------------------------
__global__ void k_build_x0(const float* __restrict__ nodes,
                           const float* __restrict__ HAts,
                           const bf16* __restrict__ hats,
                           const int* __restrict__ act,
                           float* __restrict__ x0) {
  int t = blockIdx.x * 256 + threadIdx.x;
  int c = blockIdx.y;
  if (t >= LSEQ) return;
  float v;
  if (t == LSEQ - 1) {
    v = nodes[(size_t)(G-1)*D + c];
  } else {
    int r = t / 3, m = t - 3*r;
    if (m == 0)      v = nodes[(size_t)r*D + c];
    else if (m == 1) v = HAts[(size_t)r*D + c];
    else             v = __bfloat162float(hats[(size_t)(r*PER + act[r])*D + c]);
  }
  x0[(size_t)c*LP + t] = v;
}

// ---------------------------------------------------------------------------
// K3: TCN layer, tiled. Block = 64 t x 64 out-ch, 256 threads,
// each thread 4t x 4ch. LDS: x window (32 cin x 80 t), weights [tap][cin][ch].
// y = relu(conv+b); out = relu(y + res), res = x or Wd@x.
// ---------------------------------------------------------------------------
__global__ __launch_bounds__(256) void k_tcn2(
    const float* __restrict__ xin, float* __restrict__ xout,
    const float* __restrict__ W,   // (Cout, Cin, 3)
    const float* __restrict__ b,
    const float* __restrict__ Wd,  // (Cout, Cin) or null
    int Cin, int dil) {
  __shared__ __align__(16) float xs[32][80];      // 10.0 KB
  __shared__ __align__(16) float wst[3][32][68];  // 25.5 KB
  __shared__ __align__(16) float wds[32][68];     // 8.5 KB

  const int tid = threadIdx.x;
  const int tt = tid & 15;        // t-thread: t = t0 + tt*4 + it
  const int cc = tid >> 4;        // ch-thread: ch = o0 + cc*4 + ic
  const int t0 = blockIdx.x * 64;
  const int o0 = blockIdx.y * 64;

  float acc[4][4], res[4][4];
  {
    const float4 bv = *(const float4*)&b[o0 + cc*4];
    #pragma unroll
    for (int it = 0; it < 4; ++it)
      #pragma unroll
      for (int ic = 0; ic < 4; ++ic) {
        acc[it][ic] = ((const float*)&bv)[ic];
        res[it][ic] = 0.f;
      }
  }
  const bool hasWd = (Wd != nullptr);

  const int nchunk = Cin >> 5;
  for (int c = 0; c < nchunk; ++c) {
    const int i0 = c * 32;
    __syncthreads();
    // stage x window: rows i0..i0+31, t' = t0-16 .. t0+63
    for (int idx = tid; idx < 32*80; idx += 256) {
      int r = idx / 80, j = idx - r*80;
      int tp = t0 - 16 + j;
      xs[r][j] = (tp >= 0) ? xin[(size_t)(i0 + r)*LP + tp] : 0.f;
    }
    // stage weights: wst[tap][i][o]
    for (int idx = tid; idx < 64*32; idx += 256) {
      int o = idx >> 5, i = idx & 31;
      const float* wp = &W[((size_t)(o0 + o)*Cin + i0 + i)*3];
      wst[0][i][o] = wp[0];
      wst[1][i][o] = wp[1];
      wst[2][i][o] = wp[2];
      if (hasWd) wds[i][o] = Wd[(size_t)(o0 + o)*Cin + i0 + i];
    }
    __syncthreads();

    const int base = 16 + tt*4;
    for (int i = 0; i < 32; ++i) {
      float xv[3][4];
      #pragma unroll
      for (int tap = 0; tap < 3; ++tap) {
        int off = base - (2 - tap)*dil;
        #pragma unroll
        for (int it = 0; it < 4; ++it) xv[tap][it] = xs[i][off + it];
      }
      float4 w0 = *(const float4*)&wst[0][i][cc*4];
      float4 w1 = *(const float4*)&wst[1][i][cc*4];
      float4 w2 = *(const float4*)&wst[2][i][cc*4];
      #pragma unroll
      for (int it = 0; it < 4; ++it)
        #pragma unroll
        for (int ic = 0; ic < 4; ++ic) {
          float a = acc[it][ic];
          a = fmaf(xv[0][it], ((const float*)&w0)[ic], a);
          a = fmaf(xv[1][it], ((const float*)&w1)[ic], a);
          a = fmaf(xv[2][it], ((const float*)&w2)[ic], a);
          acc[it][ic] = a;
        }
      if (hasWd) {
        float4 wd4 = *(const float4*)&wds[i][cc*4];
        #pragma unroll
        for (int it = 0; it < 4; ++it)
          #pragma unroll
          for (int ic = 0; ic < 4; ++ic)
            res[it][ic] = fmaf(xv[2][it], ((const float*)&wd4)[ic], res[it][ic]);
      }
    }
  }

  // epilogue
  #pragma unroll
  for (int ic = 0; ic < 4; ++ic) {
    int ch = o0 + cc*4 + ic;
    #pragma unroll
    for (int it = 0; it < 4; ++it) {
      int t = t0 + tt*4 + it;
      if (t < LSEQ) {
        float y = acc[it][ic] > 0.f ? acc[it][ic] : 0.f;
        float r = hasWd ? res[it][ic] : xin[(size_t)ch*LP + t];
        float v = y + r;
        xout[(size_t)ch*LP + t] = v > 0.f ? v : 0.f;
      }
    }
  }
}

// ---------------------------------------------------------------------------
// K4: Gterm[g][j] = bp1[j] + sum_{m<768} [query|hs|HAts][g][m] * Wp1[m][j]
// ---------------------------------------------------------------------------
__global__ __launch_bounds__(256) void k_gterm(
    const float* __restrict__ query, const float* __restrict__ HAts,
    const float* __restrict__ xfin,
    const float* __restrict__ Wp1, const float* __restrict__ bp1,
    float* __restrict__ Gterm) {
  __shared__ __align__(16) float s[8][768];
  const int tid = threadIdx.x;
  const int g0 = blockIdx.x * 8;
  for (int gg = 0; gg < 8; ++gg) {
    int g = g0 + gg;
    s[gg][tid]       = query[(size_t)g*D + tid];
    s[gg][256 + tid] = xfin[(size_t)tid*LP + 3*g];
    s[gg][512 + tid] = HAts[(size_t)g*D + tid];
  }
  __syncthreads();
  float acc[8][2];
  #pragma unroll
  for (int gg = 0; gg < 8; ++gg) { acc[gg][0] = 0.f; acc[gg][1] = 0.f; }
  for (int m4 = 0; m4 < 768/4; ++m4) {
    float4 sv[8];
    #pragma unroll
    for (int gg = 0; gg < 8; ++gg) sv[gg] = *(const float4*)&s[gg][m4*4];
    #pragma unroll
    for (int kk = 0; kk < 4; ++kk) {
      int m = m4*4 + kk;
      float w0 = Wp1[(size_t)m*HID + tid];
      float w1 = Wp1[(size_t)m*HID + tid + 256];
      #pragma unroll
      for (int gg = 0; gg < 8; ++gg) {
        float a = ((const float*)&sv[gg])[kk];
        acc[gg][0] = fmaf(a, w0, acc[gg][0]);
        acc[gg][1] = fmaf(a, w1, acc[gg][1]);
      }
    }
  }
  float b0 = bp1[tid], b1 = bp1[tid + 256];
  for (int gg = 0; gg < 8; ++gg) {
    Gterm[(size_t)(g0+gg)*HID + tid]       = acc[gg][0] + b0;
    Gterm[(size_t)(g0+gg)*HID + tid + 256] = acc[gg][1] + b1;
  }
}

// ---------------------------------------------------------------------------
// K5: MFMA. out[i] = relu(hats[i,:]@Wp1b + Gterm[g,:]) @ Wp2 + bp2
// block = 64 rows (4 waves x 16), loops 4 chunks of 128 cols.
// B staged 64KB/chunk from pre-tiled WBt; A-frags in regs.
// ---------------------------------------------------------------------------
__global__ __launch_bounds__(256) void k_final_mfma(
    const bf16* __restrict__ hats, const bf16* __restrict__ WBt,
    const float* __restrict__ Gterm, const float* __restrict__ Wp2,
    const float* __restrict__ bp2, float* __restrict__ out) {
  __shared__ __align__(16) unsigned short bs[32768];  // 64 KB
  __shared__ float gs[512];
  __shared__ float w2s[512];

  const int tid = threadIdx.x;
  const int wave = tid >> 6, lane = tid & 63;
  const int ln = lane & 15, quad = lane >> 4;
  const int row0 = blockIdx.x * 64;
  const int g = row0 >> 7;

  gs[tid]        = Gterm[(size_t)g*HID + tid];
  gs[tid + 256]  = Gterm[(size_t)g*HID + tid + 256];
  w2s[tid]       = Wp2[tid];
  w2s[tid + 256] = Wp2[tid + 256];

  // A fragments: 16 rows per wave, K=256 (8 frags of 8 bf16)
  bf16x8 afrag[8];
  {
    const uint4* ap = (const uint4*)(hats + (size_t)(row0 + wave*16 + ln) * D);
    #pragma unroll
    for (int kt = 0; kt < 8; ++kt) {
      uint4 t = ap[kt*4 + quad];
      afrag[kt] = *(const bf16x8*)&t;
    }
  }

  float osum[4] = {0.f, 0.f, 0.f, 0.f};

  for (int chunk = 0; chunk < 4; ++chunk) {
    __syncthreads();
    const uint4* src = (const uint4*)(WBt + (size_t)chunk * 32768);
    uint4* dst = (uint4*)bs;
    #pragma unroll
    for (int r = 0; r < 16; ++r) dst[r*256 + tid] = src[r*256 + tid];
    __syncthreads();

    #pragma unroll
    for (int nt = 0; nt < 8; ++nt) {
      f32x4 acc = {0.f, 0.f, 0.f, 0.f};
      #pragma unroll
      for (int kt = 0; kt < 8; ++kt) {
        const bf16x8 bfr = *(const bf16x8*)&bs[((nt*8 + kt)*64 + ln*4 + quad)*8];
        acc = __builtin_amdgcn_mfma_f32_16x16x32_bf16(afrag[kt], bfr, acc, 0, 0, 0);
      }
      int n = chunk*128 + nt*16 + ln;
      float gv = gs[n], wv = w2s[n];
      #pragma unroll
      for (int reg = 0; reg < 4; ++reg) {
        float h = acc[reg] + gv;
        h = h > 0.f ? h : 0.f;
        osum[reg] = fmaf(h, wv, osum[reg]);
      }
    }
  }

  // reduce across the 16 column-lanes of each quad
  #pragma unroll
  for (int reg = 0; reg < 4; ++reg) {
    float v = osum[reg];
    v += __shfl_xor(v, 1, 64);
    v += __shfl_xor(v, 2, 64);
    v += __shfl_xor(v, 4, 64);
    v += __shfl_xor(v, 8, 64);
    osum[reg] = v;
  }
  if (ln == 0) {
    float b2 = bp2[0];
    #pragma unroll
    for (int reg = 0; reg < 4; ++reg)
      out[row0 + wave*16 + quad*4 + reg] = osum[reg] + b2;
  }
}

// ---------------------------------------------------------------------------
extern "C" void kernel_launch(void* const* d_in, const int* in_sizes, int n_in,
                              void* d_out, int out_size, void* d_ws, size_t ws_size,
                              hipStream_t stream) {
  (void)in_sizes; (void)n_in; (void)out_size; (void)ws_size;
  const float* NEs   = (const float*)d_in[0];
  const float* nodes = (const float*)d_in[1];
  const float* query = (const float*)d_in[2];
  const int*   act   = (const int*)d_in[4];
  const float* Wa    = (const float*)d_in[5];
  const float* ba    = (const float*)d_in[6];
  const float* Wc0   = (const float*)d_in[7];
  const float* bc0   = (const float*)d_in[8];
  const float* Wc1   = (const float*)d_in[9];
  const float* bc1   = (const float*)d_in[10];
  const float* Wd1   = (const float*)d_in[11];
  const float* Wc2   = (const float*)d_in[12];
  const float* bc2   = (const float*)d_in[13];
  const float* Wc3   = (const float*)d_in[14];
  const float* bc3   = (const float*)d_in[15];
  const float* Wd3   = (const float*)d_in[16];
  const float* Wp1   = (const float*)d_in[17];
  const float* bp1   = (const float*)d_in[18];
  const float* Wp2   = (const float*)d_in[19];
  const float* bp2   = (const float*)d_in[20];
  float* out = (float*)d_out;

  char* ws = (char*)d_ws;
  bf16*  hats  = (bf16*)ws;  ws += (size_t)NROW * D * sizeof(bf16);
  float* HAts  = (float*)ws; ws += (size_t)G * D * sizeof(float);
  float* xa    = (float*)ws; ws += (size_t)512 * LP * sizeof(float);
  float* xb    = (float*)ws; ws += (size_t)512 * LP * sizeof(float);
  float* Gterm = (float*)ws; ws += (size_t)G * HID * sizeof(float);
  bf16*  WBt   = (bf16*)ws;  ws += (size_t)D * HID * sizeof(bf16);

  k_hats<<<G, 256, 0, stream>>>(NEs, Wa, ba, hats, HAts);
  k_wconv<<<512, 256, 0, stream>>>(Wp1, WBt);
  k_build_x0<<<dim3(6, 256), 256, 0, stream>>>(nodes, HAts, hats, act, xa);
  k_tcn2<<<dim3(24, 4), 256, 0, stream>>>(xa, xb, Wc0, bc0, nullptr, 256, 1);
  k_tcn2<<<dim3(24, 8), 256, 0, stream>>>(xb, xa, Wc1, bc1, Wd1,     256, 2);
  k_tcn2<<<dim3(24, 8), 256, 0, stream>>>(xa, xb, Wc2, bc2, nullptr, 512, 4);
  k_tcn2<<<dim3(24, 4), 256, 0, stream>>>(xb, xa, Wc3, bc3, Wd3,     512, 8);
  k_gterm<<<G/8, 256, 0, stream>>>(query, HAts, xa, Wp1, bp1, Gterm);
  k_final_mfma<<<NROW/64, 256, 0, stream>>>(hats, WBt, Gterm, Wp2, bp2, out);
}